// Round 8
// baseline (378.352 us; speedup 1.0000x reference)
//
#include <hip/hip_runtime.h>

#define D_ 1024
#define T_ 2048
#define B_ 2
#define H_ 16
#define MLP_ 4096
#define NTOK (B_*T_)   // 4096
#define QG 256         // global q-rows per batch (T/8)
#define L2E 1.44269504088896340736f

typedef float f32x4 __attribute__((ext_vector_type(4)));
typedef __bf16 bf16x8 __attribute__((ext_vector_type(8)));

__device__ __forceinline__ unsigned short f2bf(float f) {
  unsigned int u = __float_as_uint(f);
  u += 0x7fff + ((u >> 16) & 1);
  return (unsigned short)(u >> 16);
}

__device__ __forceinline__ float wave_sum(float v) {
  for (int o = 32; o > 0; o >>= 1) v += __shfl_down(v, o, 64);
  return v;
}

// async global->LDS, 16B per lane; LDS dest = wave-uniform base + lane*16
__device__ __forceinline__ void gload16(const unsigned short* g, unsigned short* l) {
  __builtin_amdgcn_global_load_lds(
      (const __attribute__((address_space(1))) void*)g,
      (__attribute__((address_space(3))) void*)l, 16, 0, 0);
}

// ---------------- all 4 weight casts in one launch -----------------------
#define N4_WIN  786432   // 3*D*D/4
#define N4_WOUT 262144   // D*D/4
#define N4_W1   1048576  // MLP*D/4
#define N4_W2   1048576  // D*MLP/4
__global__ void cast_all_kernel(const float* __restrict__ w_in,
                                const float* __restrict__ w_out,
                                const float* __restrict__ w1,
                                const float* __restrict__ w2,
                                unsigned short* __restrict__ o_in,
                                unsigned short* __restrict__ o_out,
                                unsigned short* __restrict__ o1,
                                unsigned short* __restrict__ o2) {
  int i = blockIdx.x * 256 + threadIdx.x;
  const float* src; unsigned short* dst; int j = i;
  if (i < N4_WIN) { src = w_in; dst = o_in; }
  else if ((j -= N4_WIN) < N4_WOUT) { src = w_out; dst = o_out; }
  else if ((j -= N4_WOUT) < N4_W1) { src = w1; dst = o1; }
  else { j -= N4_W1; src = w2; dst = o2; }
  float4 v = ((const float4*)src)[j];
  ushort4 o;
  o.x = f2bf(v.x); o.y = f2bf(v.y); o.z = f2bf(v.z); o.w = f2bf(v.w);
  ((ushort4*)dst)[j] = o;
}

// ---------------- LayerNorm (one block per row of D=1024), out bf16 ------
__global__ void ln_kernel(const float* __restrict__ x, const float* __restrict__ g,
                          const float* __restrict__ b, unsigned short* __restrict__ out) {
  int row = blockIdx.x;
  int tid = threadIdx.x;
  int wave = tid >> 6, lane = tid & 63;
  float4 v = ((const float4*)(x + (size_t)row * D_))[tid];
  float s  = v.x + v.y + v.z + v.w;
  float s2 = v.x*v.x + v.y*v.y + v.z*v.z + v.w*v.w;
  s = wave_sum(s); s2 = wave_sum(s2);
  __shared__ float r1[4], r2[4];
  if (lane == 0) { r1[wave] = s; r2[wave] = s2; }
  __syncthreads();
  float ts  = r1[0] + r1[1] + r1[2] + r1[3];
  float ts2 = r2[0] + r2[1] + r2[2] + r2[3];
  float mean = ts * (1.0f / D_);
  float var  = ts2 * (1.0f / D_) - mean * mean;
  float rs = rsqrtf(var + 1e-5f);
  float4 gv = ((const float4*)g)[tid];
  float4 bv = ((const float4*)b)[tid];
  ushort4 o;
  o.x = f2bf((v.x - mean) * rs * gv.x + bv.x);
  o.y = f2bf((v.y - mean) * rs * gv.y + bv.y);
  o.z = f2bf((v.z - mean) * rs * gv.z + bv.z);
  o.w = f2bf((v.w - mean) * rs * gv.w + bv.w);
  ((ushort4*)(out + (size_t)row * D_))[tid] = o;
}

// ---- out-proj reduce (4 slabs) + residual + bias + LayerNorm2 -----------
__global__ void reduce_ln_kernel(const float* __restrict__ part,
                                 const float* __restrict__ x,
                                 const float* __restrict__ bias,
                                 const float* __restrict__ g,
                                 const float* __restrict__ b,
                                 float* __restrict__ x1,
                                 unsigned short* __restrict__ xn2) {
  int row = blockIdx.x;
  int tid = threadIdx.x;
  int wave = tid >> 6, lane = tid & 63;
  size_t base = (size_t)row * (D_ / 4) + tid;
  float4 v = ((const float4*)x)[base];
  float4 bo = ((const float4*)bias)[tid];
  v.x += bo.x; v.y += bo.y; v.z += bo.z; v.w += bo.w;
#pragma unroll
  for (int c = 0; c < 4; ++c) {
    float4 p = ((const float4*)part)[(size_t)c * (NTOK * (D_ / 4)) + base];
    v.x += p.x; v.y += p.y; v.z += p.z; v.w += p.w;
  }
  ((float4*)x1)[base] = v;
  float s  = v.x + v.y + v.z + v.w;
  float s2 = v.x*v.x + v.y*v.y + v.z*v.z + v.w*v.w;
  s = wave_sum(s); s2 = wave_sum(s2);
  __shared__ float r1[4], r2[4];
  if (lane == 0) { r1[wave] = s; r2[wave] = s2; }
  __syncthreads();
  float ts  = r1[0] + r1[1] + r1[2] + r1[3];
  float ts2 = r2[0] + r2[1] + r2[2] + r2[3];
  float mean = ts * (1.0f / D_);
  float var  = ts2 * (1.0f / D_) - mean * mean;
  float rs = rsqrtf(var + 1e-5f);
  float4 gv = ((const float4*)g)[tid];
  float4 bv = ((const float4*)b)[tid];
  ushort4 o;
  o.x = f2bf((v.x - mean) * rs * gv.x + bv.x);
  o.y = f2bf((v.y - mean) * rs * gv.y + bv.y);
  o.z = f2bf((v.z - mean) * rs * gv.z + bv.z);
  o.w = f2bf((v.w - mean) * rs * gv.w + bv.w);
  ((ushort4*)xn2)[base] = o;
}

// ---- final reduce: out = x1 + b2 + sum_{c<4} part[c]  (f32, x4) ---------
__global__ void reduce_out_kernel(const float* __restrict__ part,
                                  const float* __restrict__ x1,
                                  const float* __restrict__ bias,
                                  float* __restrict__ out) {
  int i = blockIdx.x * 256 + threadIdx.x;
  float4 v = ((const float4*)x1)[i];
  float4 bo = ((const float4*)bias)[i & (D_ / 4 - 1)];
  v.x += bo.x; v.y += bo.y; v.z += bo.z; v.w += bo.w;
#pragma unroll
  for (int c = 0; c < 4; ++c) {
    float4 p = ((const float4*)part)[(size_t)c * (NTOK * (D_ / 4)) + i];
    v.x += p.x; v.y += p.y; v.z += p.z; v.w += p.w;
  }
  ((float4*)out)[i] = v;
}

// ---------------- Generic bf16 MFMA GEMM (r6 proven structure) -----------
// C[m,n] = sum_k A[m,k] * B[n,k].  M, N multiples of 128.
// EPI: 2 = bf16 out, gelu(acc+bias); 7 = f32 plain store into slab bz;
//      8 = QKV routing (q->Qg global rows, k->Kh, v->Cv compact [NTOK,D])
// SWIZ: 1 = y-fast (skinny N), 2 = 2x4 super-tiles
// kshift: blockIdx.z = (batch << kshift) | kchunk; K = per-chunk depth
template<int EPI, int SWIZ, int LDA, int LDB, int LDC>
__global__ __launch_bounds__(256)
void gemm_kernel(const unsigned short* __restrict__ A, size_t sA,
                 const unsigned short* __restrict__ Bm, size_t sB,
                 void* __restrict__ Cv, size_t sC,
                 const float* __restrict__ bias,
                 unsigned short* __restrict__ aux1,   // EPI8: Qg
                 unsigned short* __restrict__ aux2,   // EPI8: Kh
                 int K, int nx, int ny, int kshift) {
  __shared__ __align__(16) unsigned short As[128 * 32];
  __shared__ __align__(16) unsigned short Bs[128 * 32];
  const int flat = blockIdx.x;
  int bx, by;
  if (SWIZ == 1) {
    bx = flat / ny; by = flat - bx * ny;
  } else {
    const int sxc = nx >> 1;
    const int nSuper = sxc * (ny >> 2);
    int s = flat % nSuper, pos = flat / nSuper;
    int sx = s % sxc, sy = s / sxc;
    bx = sx * 2 + (pos & 1);
    by = sy * 4 + (pos >> 1);
  }
  const int bz = blockIdx.z;
  const int batch = bz >> kshift;
  const int kOff  = (bz & ((1 << kshift) - 1)) * K;
  const int m0 = by * 128;
  const int n0 = bx * 128;
  const int tid = threadIdx.x;
  const int lane = tid & 63, wave = tid >> 6;
  const int wm = (wave >> 1) * 64, wn = (wave & 1) * 64;
  const int fr = lane & 15, q = lane >> 4;
  const int fchunk = (q ^ (fr & 3) ^ ((fr >> 2) & 3)) << 3;

  // per-thread staging pointers (strength-reduced: += 32 per K-iter)
  const int r0 = tid >> 2,  c0 = ((tid & 3) ^ (r0 & 3) ^ ((r0 >> 2) & 3)) << 3;
  const int l1 = tid + 256;
  const int r1 = l1 >> 2,   c1 = ((l1 & 3) ^ (r1 & 3) ^ ((r1 >> 2) & 3)) << 3;
  const unsigned short* a0 = A  + (size_t)batch * sA + kOff + (size_t)(m0 + r0) * LDA + c0;
  const unsigned short* a1 = A  + (size_t)batch * sA + kOff + (size_t)(m0 + r1) * LDA + c1;
  const unsigned short* b0 = Bm + (size_t)batch * sB + kOff + (size_t)(n0 + r0) * LDB + c0;
  const unsigned short* b1 = Bm + (size_t)batch * sB + kOff + (size_t)(n0 + r1) * LDB + c1;
  unsigned short* sa0 = &As[tid * 8];
  unsigned short* sa1 = &As[l1 * 8];
  unsigned short* sb0 = &Bs[tid * 8];
  unsigned short* sb1 = &Bs[l1 * 8];

  // loop-invariant LDS fragment pointers
  const unsigned short* pa[4];
  const unsigned short* pb[4];
#pragma unroll
  for (int i = 0; i < 4; ++i) {
    pa[i] = &As[(wm + i * 16 + fr) * 32 + fchunk];
    pb[i] = &Bs[(wn + i * 16 + fr) * 32 + fchunk];
  }

  f32x4 acc[4][4] = {};
  for (int ko = 0; ko < K; ko += 32) {
    __syncthreads();
    gload16(a0, sa0); gload16(a1, sa1);
    gload16(b0, sb0); gload16(b1, sb1);
    a0 += 32; a1 += 32; b0 += 32; b1 += 32;
    __syncthreads();
    bf16x8 af[4], bfr[4];
#pragma unroll
    for (int i = 0; i < 4; ++i) af[i]  = *(const bf16x8*)pa[i];
#pragma unroll
    for (int j = 0; j < 4; ++j) bfr[j] = *(const bf16x8*)pb[j];
#pragma unroll
    for (int i = 0; i < 4; ++i)
#pragma unroll
      for (int j = 0; j < 4; ++j)
        acc[i][j] = __builtin_amdgcn_mfma_f32_16x16x32_bf16(af[i], bfr[j], acc[i][j], 0, 0, 0);
  }

  const int col = lane & 15, rbase = (lane >> 4) * 4;
#pragma unroll
  for (int i = 0; i < 4; ++i) {
#pragma unroll
    for (int j = 0; j < 4; ++j) {
      int gn = n0 + wn + j * 16 + col;
      int gmb = m0 + wm + i * 16 + rbase;
      float bv = (EPI == 2 || EPI == 8) ? bias[gn] : 0.0f;
#pragma unroll
      for (int r = 0; r < 4; ++r) {
        int gm = gmb + r;
        float v = acc[i][j][r] + bv;
        if (EPI == 2) {
          float gl = 0.5f * v * (1.0f + erff(v * 0.70710678118f));
          ((unsigned short*)Cv)[(size_t)gm * LDC + gn] = f2bf(gl);
        } else if (EPI == 7) {
          ((float*)Cv)[(size_t)bz * sC + (size_t)gm * LDC + gn] = v;
        } else if (EPI == 8) {
          int sec = gn >> 10;          // 0=q 1=k 2=v
          int hh = (gn >> 6) & (H_ - 1);
          int dd = gn & 63;
          int t = gm & (T_ - 1);
          int b = gm >> 11;
          unsigned short bf = f2bf(v);
          if (sec == 0) {
            if (!(t & 7))
              aux1[(((size_t)(b * H_ + hh)) * QG + (t >> 3)) * 64 + dd] = bf;
          } else if (sec == 1) {
            aux2[(((size_t)(b * H_ + hh)) * T_ + t) * 64 + dd] = bf;
          } else {
            ((unsigned short*)Cv)[(size_t)gm * D_ + (gn - 2 * D_)] = bf;
          }
        }
      }
    }
  }
}

// ---------------- V transpose: v[tok, D] bf16 -> Vt[bh][d][t] bf16 -------
__global__ void vtrans_kernel(const unsigned short* __restrict__ vcomp,
                              unsigned short* __restrict__ Vt) {
  int blk = blockIdx.x;          // B*H*(T/64) = 1024
  int tchunk = blk & 31;
  int bh = blk >> 5;
  int h = bh & (H_ - 1), b = bh >> 4;
  int t0 = tchunk * 64;
  __shared__ unsigned short ls[64][66];
  int tid = threadIdx.x;
#pragma unroll
  for (int it = 0; it < 16; ++it) {
    int linear = it * 256 + tid;
    int d = linear & 63, tl = linear >> 6;
    ls[d][tl] = vcomp[((size_t)(b * T_ + t0 + tl)) * D_ + h * 64 + d];
  }
  __syncthreads();
#pragma unroll
  for (int it = 0; it < 16; ++it) {
    int linear = it * 256 + tid;
    int tl = linear & 63, d = linear >> 6;
    Vt[((size_t)(bh * 64 + d)) * T_ + t0 + tl] = ls[d][tl];
  }
}

// ---------------- Flash attention for global q-rows ----------------------
// grid (kchunk=4, qtile=4, bh=32), block 256 (4 waves; wave w owns q-rows
// qt*64 + w*16 .. +16). Each k-chunk covers 512 keys (4 tiles of 128).
__global__ __launch_bounds__(256)
void flash_kernel(const unsigned short* __restrict__ Qg,   // [bh][256][64]
                  const unsigned short* __restrict__ Kh,   // [bh][2048][64]
                  const unsigned short* __restrict__ Vt,   // [bh][64][2048]
                  float* __restrict__ Opart,               // [bh][4][256][64]
                  float* __restrict__ ml) {                // [bh][4][256][2]
  const int kc = blockIdx.x, qt = blockIdx.y, bh = blockIdx.z;
  const int tid = threadIdx.x;
  const int lane = tid & 63, w = tid >> 6;
  const int fr = lane & 15, quad = lane >> 4;

  __shared__ __align__(16) unsigned short Qs[64 * 64];     // 8 KB
  __shared__ __align__(16) unsigned short Ks[128 * 64];    // 16 KB
  __shared__ __align__(16) unsigned short Vs[64 * 128];    // 16 KB
  __shared__ __align__(16) unsigned short Ps[4 * 16 * 128];// 16 KB

  const unsigned short* Qbase = Qg + ((size_t)bh * 256 + qt * 64) * 64;
#pragma unroll
  for (int p = 0; p < 2; ++p) {
    int linear = p * 256 + tid;
    int r = linear >> 3, c = linear & 7;
    gload16(Qbase + r * 64 + (c ^ (r & 7)) * 8, &Qs[linear * 8]);
  }

  float m_run[4], l_run[4];
  f32x4 O[4] = {};
#pragma unroll
  for (int r = 0; r < 4; ++r) { m_run[r] = -3.0e38f; l_run[r] = 0.f; }

  const unsigned short* Kc = Kh + ((size_t)bh * T_ + kc * 512) * 64;
  const unsigned short* Vc = Vt + (size_t)bh * 64 * T_ + kc * 512;
  unsigned short* Pw = &Ps[w * 2048];
  const int arow = w * 16 + fr;

  for (int kt = 0; kt < 4; ++kt) {
    __syncthreads();
#pragma unroll
    for (int p = 0; p < 4; ++p) {
      int linear = p * 256 + tid;
      int r = linear >> 3, c = linear & 7;
      gload16(Kc + (size_t)(kt * 128 + r) * 64 + (c ^ (r & 7)) * 8, &Ks[linear * 8]);
    }
#pragma unroll
    for (int p = 0; p < 4; ++p) {
      int linear = p * 256 + tid;
      int r = linear >> 4, c = linear & 15;
      gload16(Vc + (size_t)r * T_ + kt * 128 + (c ^ (r & 7)) * 8, &Vs[linear * 8]);
    }
    __syncthreads();

    f32x4 s[8] = {};
    bf16x8 aq[2];
#pragma unroll
    for (int ks = 0; ks < 2; ++ks)
      aq[ks] = *(const bf16x8*)&Qs[arow * 64 + ((ks * 4 + quad) ^ (fr & 7)) * 8];
#pragma unroll
    for (int nf = 0; nf < 8; ++nf) {
      int krow = nf * 16 + fr;
#pragma unroll
      for (int ks = 0; ks < 2; ++ks) {
        bf16x8 bk = *(const bf16x8*)&Ks[krow * 64 + ((ks * 4 + quad) ^ (fr & 7)) * 8];
        s[nf] = __builtin_amdgcn_mfma_f32_16x16x32_bf16(aq[ks], bk, s[nf], 0, 0, 0);
      }
    }
    float alpha[4], rowsum[4];
#pragma unroll
    for (int r = 0; r < 4; ++r) {
      float mt = -3.0e38f;
#pragma unroll
      for (int nf = 0; nf < 8; ++nf) { s[nf][r] *= 0.125f; mt = fmaxf(mt, s[nf][r]); }
#pragma unroll
      for (int x = 1; x < 16; x <<= 1) mt = fmaxf(mt, __shfl_xor(mt, x, 64));
      float mn = fmaxf(m_run[r], mt);
      alpha[r] = exp2f((m_run[r] - mn) * L2E);
      m_run[r] = mn;
      rowsum[r] = 0.f;
    }
#pragma unroll
    for (int nf = 0; nf < 8; ++nf)
#pragma unroll
      for (int r = 0; r < 4; ++r) {
        float p = exp2f((s[nf][r] - m_run[r]) * L2E);
        s[nf][r] = p; rowsum[r] += p;
      }
#pragma unroll
    for (int r = 0; r < 4; ++r) {
#pragma unroll
      for (int x = 1; x < 16; x <<= 1) rowsum[r] += __shfl_xor(rowsum[r], x, 64);
      l_run[r] = l_run[r] * alpha[r] + rowsum[r];
    }
#pragma unroll
    for (int nf = 0; nf < 8; ++nf)
#pragma unroll
      for (int r = 0; r < 4; ++r) {
        int m = quad * 4 + r;
        int c = nf * 2 + (fr >> 3);
        Pw[m * 128 + ((c ^ (m & 7)) * 8) + (fr & 7)] = f2bf(s[nf][r]);
      }
#pragma unroll
    for (int nf2 = 0; nf2 < 4; ++nf2)
#pragma unroll
      for (int r = 0; r < 4; ++r) O[nf2][r] *= alpha[r];
#pragma unroll
    for (int ks2 = 0; ks2 < 4; ++ks2) {
      bf16x8 ap = *(const bf16x8*)&Pw[fr * 128 + (((ks2 * 4 + quad) ^ (fr & 7)) * 8)];
#pragma unroll
      for (int nf2 = 0; nf2 < 4; ++nf2) {
        int vrow = nf2 * 16 + fr;
        bf16x8 bv = *(const bf16x8*)&Vs[vrow * 128 + (((ks2 * 4 + quad) ^ (fr & 7)) * 8)];
        O[nf2] = __builtin_amdgcn_mfma_f32_16x16x32_bf16(ap, bv, O[nf2], 0, 0, 0);
      }
    }
  }

  int qbase = qt * 64 + w * 16;
  float* Ob = Opart + (((size_t)bh * 4 + kc) * 256 + qbase) * 64;
#pragma unroll
  for (int nf2 = 0; nf2 < 4; ++nf2)
#pragma unroll
    for (int r = 0; r < 4; ++r)
      Ob[(size_t)(quad * 4 + r) * 64 + nf2 * 16 + fr] = O[nf2][r];
  if (fr == 0) {
#pragma unroll
    for (int r = 0; r < 4; ++r) {
      size_t mi = ((((size_t)bh * 4 + kc) * 256) + qbase + quad * 4 + r) * 2;
      ml[mi] = m_run[r]; ml[mi + 1] = l_run[r];
    }
  }
}

// ---- combine 4 k-chunk flash partials, scatter into v buffer ------------
__global__ void combine_kernel(const float* __restrict__ Opart,
                               const float* __restrict__ ml,
                               unsigned short* __restrict__ vcomp) {
  int idx = blockIdx.x * 256 + threadIdx.x;  // B*QG*D = 2^19
  int c = idx & (D_ - 1);
  int qi = (idx >> 10) & (QG - 1);
  int b = idx >> 18;
  int h = c >> 6, d = c & 63;
  int bh = b * H_ + h;
  float m[4], l[4];
  float M = -3.0e38f;
#pragma unroll
  for (int ch = 0; ch < 4; ++ch) {
    size_t r = ((size_t)bh * 4 + ch) * 256 + qi;
    m[ch] = ml[r * 2]; l[ch] = ml[r * 2 + 1];
    M = fmaxf(M, m[ch]);
  }
  float osum = 0.f, lsum = 0.f;
#pragma unroll
  for (int ch = 0; ch < 4; ++ch) {
    size_t r = ((size_t)bh * 4 + ch) * 256 + qi;
    float wgt = exp2f((m[ch] - M) * L2E);
    osum += wgt * Opart[r * 64 + d];
    lsum += wgt * l[ch];
  }
  vcomp[((size_t)(b * T_ + qi * 8)) * D_ + c] = f2bf(osum / lsum);
}

extern "C" void kernel_launch(void* const* d_in, const int* in_sizes, int n_in,
                              void* d_out, int out_size, void* d_ws, size_t ws_size,
                              hipStream_t stream) {
  const float* x     = (const float*)d_in[0];
  const float* w_in  = (const float*)d_in[1];
  const float* b_in  = (const float*)d_in[2];
  const float* w_out = (const float*)d_in[3];
  const float* b_out = (const float*)d_in[4];
  const float* w1    = (const float*)d_in[5];
  const float* b1    = (const float*)d_in[6];
  const float* w2    = (const float*)d_in[7];
  const float* b2    = (const float*)d_in[8];
  const float* ln1_g = (const float*)d_in[9];
  const float* ln1_b = (const float*)d_in[10];
  const float* ln2_g = (const float*)d_in[11];
  const float* ln2_b = (const float*)d_in[12];
  float* out = (float*)d_out;

  char* ws = (char*)d_ws;
  size_t off = 0;
  auto alloc = [&](size_t bytes) -> void* {
    void* p = ws + off;
    off += (bytes + 255) & ~(size_t)255;
    return p;
  };
  unsigned short* xn    = (unsigned short*)alloc((size_t)NTOK * D_ * 2);
  unsigned short* vcomp = (unsigned short*)alloc((size_t)NTOK * D_ * 2);  // v, then o
  unsigned short* w_inb = (unsigned short*)alloc((size_t)3 * D_ * D_ * 2);
  unsigned short* w_outb= (unsigned short*)alloc((size_t)D_ * D_ * 2);
  unsigned short* w1b   = (unsigned short*)alloc((size_t)MLP_ * D_ * 2);
  unsigned short* w2b   = (unsigned short*)alloc((size_t)D_ * MLP_ * 2);
  unsigned short* Qg    = (unsigned short*)alloc((size_t)B_ * H_ * QG * 64 * 2);
  unsigned short* Kh    = (unsigned short*)alloc((size_t)B_ * H_ * T_ * 64 * 2);
  unsigned short* Vt    = (unsigned short*)alloc((size_t)B_ * H_ * 64 * T_ * 2);
  float*          Opart = (float*)         alloc((size_t)B_ * H_ * 4 * QG * 64 * 4);
  float*          mlbuf = (float*)         alloc((size_t)B_ * H_ * 4 * QG * 2 * 4);
  float*          x1    = (float*)         alloc((size_t)NTOK * D_ * 4);
  unsigned short* xn2   = (unsigned short*)alloc((size_t)NTOK * D_ * 2);
  unsigned short* h     = (unsigned short*)alloc((size_t)NTOK * MLP_ * 2);
  float*          P4    = (float*)         alloc((size_t)4 * NTOK * D_ * 4);

  // 1. weight casts (single launch)
  cast_all_kernel<<<(N4_WIN + N4_WOUT + N4_W1 + N4_W2) / 256, 256, 0, stream>>>(
      w_in, w_out, w1, w2, w_inb, w_outb, w1b, w2b);

  // 2. LN1
  ln_kernel<<<NTOK, 256, 0, stream>>>(x, ln1_g, ln1_b, xn);

  // 3. QKV = xn @ w_in^T + b_in; epilogue routes q->Qg, k->Kh, v->vcomp
  gemm_kernel<8, 2, D_, D_, 3 * D_><<<dim3(24 * 32, 1, 1), 256, 0, stream>>>(
      xn, 0, w_inb, 0, vcomp, 0, b_in, Qg, Kh, D_, 24, 32, 0);

  // 4. V transpose for PV B-operand
  vtrans_kernel<<<1024, 256, 0, stream>>>(vcomp, Vt);

  // 5. flash attention over global q-rows (k-split x4 -> 512 blocks)
  flash_kernel<<<dim3(4, 4, 32), 256, 0, stream>>>(Qg, Kh, Vt, Opart, mlbuf);

  // 6. combine k-chunks, scatter into v buffer (o = v elsewhere)
  combine_kernel<<<2048, 256, 0, stream>>>(Opart, mlbuf, vcomp);

  // 7. P4[c] = o @ w_out^T (k-chunk c)  (split-K x4 -> 1024 blocks, 4/CU)
  gemm_kernel<7, 1, D_, D_, D_><<<dim3(8 * 32, 1, 4), 256, 0, stream>>>(
      vcomp, 0, w_outb, 0, P4, (size_t)NTOK * D_, nullptr, nullptr, nullptr,
      256, 8, 32, 2);

  // 8. x1 = x + b_out + sum(P4); xn2 = LN2(x1)   (fused reduce+LN)
  reduce_ln_kernel<<<NTOK, 256, 0, stream>>>(P4, x, b_out, ln2_g, ln2_b, x1, xn2);

  // 9. h = gelu(xn2 @ w1^T + b1) -> bf16 [4096, 4096]
  gemm_kernel<2, 2, D_, D_, MLP_><<<dim3(32 * 32, 1, 1), 256, 0, stream>>>(
      xn2, 0, w1b, 0, h, 0, b1, nullptr, nullptr, D_, 32, 32, 0);

  // 10. P4[c] = h @ w2^T (k-chunk c)  (split-K x4 -> 1024 blocks, 4/CU)
  gemm_kernel<7, 1, MLP_, MLP_, D_><<<dim3(8 * 32, 1, 4), 256, 0, stream>>>(
      h, 0, w2b, 0, P4, (size_t)NTOK * D_, nullptr, nullptr, nullptr,
      1024, 8, 32, 2);

  // 11. out = x1 + b2 + sum(P4)
  reduce_out_kernel<<<4096, 256, 0, stream>>>(P4, x1, b2, out);
}

// Round 9
// 335.772 us; speedup vs baseline: 1.1268x; 1.1268x over previous
//
#include <hip/hip_runtime.h>

#define D_ 1024
#define T_ 2048
#define B_ 2
#define H_ 16
#define MLP_ 4096
#define NTOK (B_*T_)   // 4096
#define QG 256         // global q-rows per batch (T/8)
#define L2E 1.44269504088896340736f

typedef float f32x4 __attribute__((ext_vector_type(4)));
typedef __bf16 bf16x8 __attribute__((ext_vector_type(8)));

__device__ __forceinline__ unsigned short f2bf(float f) {
  unsigned int u = __float_as_uint(f);
  u += 0x7fff + ((u >> 16) & 1);
  return (unsigned short)(u >> 16);
}

__device__ __forceinline__ float wave_sum(float v) {
  for (int o = 32; o > 0; o >>= 1) v += __shfl_down(v, o, 64);
  return v;
}

// async global->LDS, 16B per lane; LDS dest = wave-uniform base + lane*16
__device__ __forceinline__ void gload16(const unsigned short* g, unsigned short* l) {
  __builtin_amdgcn_global_load_lds(
      (const __attribute__((address_space(1))) void*)g,
      (__attribute__((address_space(3))) void*)l, 16, 0, 0);
}

// ---------------- all 4 weight casts in one launch -----------------------
#define N4_WIN  786432   // 3*D*D/4
#define N4_WOUT 262144   // D*D/4
#define N4_W1   1048576  // MLP*D/4
#define N4_W2   1048576  // D*MLP/4
__global__ void cast_all_kernel(const float* __restrict__ w_in,
                                const float* __restrict__ w_out,
                                const float* __restrict__ w1,
                                const float* __restrict__ w2,
                                unsigned short* __restrict__ o_in,
                                unsigned short* __restrict__ o_out,
                                unsigned short* __restrict__ o1,
                                unsigned short* __restrict__ o2) {
  int i = blockIdx.x * 256 + threadIdx.x;
  const float* src; unsigned short* dst; int j = i;
  if (i < N4_WIN) { src = w_in; dst = o_in; }
  else if ((j -= N4_WIN) < N4_WOUT) { src = w_out; dst = o_out; }
  else if ((j -= N4_WOUT) < N4_W1) { src = w1; dst = o1; }
  else { j -= N4_W1; src = w2; dst = o2; }
  float4 v = ((const float4*)src)[j];
  ushort4 o;
  o.x = f2bf(v.x); o.y = f2bf(v.y); o.z = f2bf(v.z); o.w = f2bf(v.w);
  ((ushort4*)dst)[j] = o;
}

// ---------------- LayerNorm (one block per row of D=1024), out bf16 ------
__global__ void ln_kernel(const float* __restrict__ x, const float* __restrict__ g,
                          const float* __restrict__ b, unsigned short* __restrict__ out) {
  int row = blockIdx.x;
  int tid = threadIdx.x;
  int wave = tid >> 6, lane = tid & 63;
  float4 v = ((const float4*)(x + (size_t)row * D_))[tid];
  float s  = v.x + v.y + v.z + v.w;
  float s2 = v.x*v.x + v.y*v.y + v.z*v.z + v.w*v.w;
  s = wave_sum(s); s2 = wave_sum(s2);
  __shared__ float r1[4], r2[4];
  if (lane == 0) { r1[wave] = s; r2[wave] = s2; }
  __syncthreads();
  float ts  = r1[0] + r1[1] + r1[2] + r1[3];
  float ts2 = r2[0] + r2[1] + r2[2] + r2[3];
  float mean = ts * (1.0f / D_);
  float var  = ts2 * (1.0f / D_) - mean * mean;
  float rs = rsqrtf(var + 1e-5f);
  float4 gv = ((const float4*)g)[tid];
  float4 bv = ((const float4*)b)[tid];
  ushort4 o;
  o.x = f2bf((v.x - mean) * rs * gv.x + bv.x);
  o.y = f2bf((v.y - mean) * rs * gv.y + bv.y);
  o.z = f2bf((v.z - mean) * rs * gv.z + bv.z);
  o.w = f2bf((v.w - mean) * rs * gv.w + bv.w);
  ((ushort4*)(out + (size_t)row * D_))[tid] = o;
}

// ---- out-proj reduce (2 slabs) + residual + bias + LayerNorm2 -----------
__global__ void reduce_ln_kernel(const float* __restrict__ part,
                                 const float* __restrict__ x,
                                 const float* __restrict__ bias,
                                 const float* __restrict__ g,
                                 const float* __restrict__ b,
                                 float* __restrict__ x1,
                                 unsigned short* __restrict__ xn2) {
  int row = blockIdx.x;
  int tid = threadIdx.x;
  int wave = tid >> 6, lane = tid & 63;
  size_t base = (size_t)row * (D_ / 4) + tid;
  float4 v = ((const float4*)x)[base];
  float4 bo = ((const float4*)bias)[tid];
  v.x += bo.x; v.y += bo.y; v.z += bo.z; v.w += bo.w;
#pragma unroll
  for (int c = 0; c < 2; ++c) {
    float4 p = ((const float4*)part)[(size_t)c * (NTOK * (D_ / 4)) + base];
    v.x += p.x; v.y += p.y; v.z += p.z; v.w += p.w;
  }
  ((float4*)x1)[base] = v;
  float s  = v.x + v.y + v.z + v.w;
  float s2 = v.x*v.x + v.y*v.y + v.z*v.z + v.w*v.w;
  s = wave_sum(s); s2 = wave_sum(s2);
  __shared__ float r1[4], r2[4];
  if (lane == 0) { r1[wave] = s; r2[wave] = s2; }
  __syncthreads();
  float ts  = r1[0] + r1[1] + r1[2] + r1[3];
  float ts2 = r2[0] + r2[1] + r2[2] + r2[3];
  float mean = ts * (1.0f / D_);
  float var  = ts2 * (1.0f / D_) - mean * mean;
  float rs = rsqrtf(var + 1e-5f);
  float4 gv = ((const float4*)g)[tid];
  float4 bv = ((const float4*)b)[tid];
  ushort4 o;
  o.x = f2bf((v.x - mean) * rs * gv.x + bv.x);
  o.y = f2bf((v.y - mean) * rs * gv.y + bv.y);
  o.z = f2bf((v.z - mean) * rs * gv.z + bv.z);
  o.w = f2bf((v.w - mean) * rs * gv.w + bv.w);
  ((ushort4*)xn2)[base] = o;
}

// ---- final reduce: out = x1 + b2 + sum_{c<2} part[c]  (f32, x4) ---------
__global__ void reduce_out_kernel(const float* __restrict__ part,
                                  const float* __restrict__ x1,
                                  const float* __restrict__ bias,
                                  float* __restrict__ out) {
  int i = blockIdx.x * 256 + threadIdx.x;
  float4 v = ((const float4*)x1)[i];
  float4 bo = ((const float4*)bias)[i & (D_ / 4 - 1)];
  v.x += bo.x; v.y += bo.y; v.z += bo.z; v.w += bo.w;
#pragma unroll
  for (int c = 0; c < 2; ++c) {
    float4 p = ((const float4*)part)[(size_t)c * (NTOK * (D_ / 4)) + i];
    v.x += p.x; v.y += p.y; v.z += p.z; v.w += p.w;
  }
  ((float4*)out)[i] = v;
}

// ---------------- Generic bf16 MFMA GEMM, BK=64 --------------------------
// C[m,n] = sum_k A[m,k] * B[n,k].  M, N multiples of 128; K mult of 64.
// 128x64 tiles (32 KB LDS total): half the barriers of BK=32 for the same
// staged bytes (the per-barrier vmcnt(0) drain is the structural stall).
// Chunk swizzle: 16B chunk at row r, LDS pos p holds global chunk p^(r&7);
// fragment ds_read_b128 spreads 8 positions over 16 lanes -> 2-way (free).
// EPI: 2 = bf16 out, gelu(acc+bias) [tanh-approx, err<3e-3];
//      7 = f32 plain store into slab bz;
//      8 = QKV routing (q->Qg global rows, k->Kh, v->Cv compact [NTOK,D])
// SWIZ: 1 = y-fast (skinny N), 2 = 2x4 super-tiles
// kshift: blockIdx.z = (batch << kshift) | kchunk; K = per-chunk depth
template<int EPI, int SWIZ, int LDA, int LDB, int LDC>
__global__ __launch_bounds__(256)
void gemm_kernel(const unsigned short* __restrict__ A, size_t sA,
                 const unsigned short* __restrict__ Bm, size_t sB,
                 void* __restrict__ Cv, size_t sC,
                 const float* __restrict__ bias,
                 unsigned short* __restrict__ aux1,   // EPI8: Qg
                 unsigned short* __restrict__ aux2,   // EPI8: Kh
                 int K, int nx, int ny, int kshift) {
  __shared__ __align__(16) unsigned short As[128 * 64];
  __shared__ __align__(16) unsigned short Bs[128 * 64];
  const int flat = blockIdx.x;
  int bx, by;
  if (SWIZ == 1) {
    bx = flat / ny; by = flat - bx * ny;
  } else {
    const int sxc = nx >> 1;
    const int nSuper = sxc * (ny >> 2);
    int s = flat % nSuper, pos = flat / nSuper;
    int sx = s % sxc, sy = s / sxc;
    bx = sx * 2 + (pos & 1);
    by = sy * 4 + (pos >> 1);
  }
  const int bz = blockIdx.z;
  const int batch = bz >> kshift;
  const int kOff  = (bz & ((1 << kshift) - 1)) * K;
  const int m0 = by * 128;
  const int n0 = bx * 128;
  const int tid = threadIdx.x;
  const int lane = tid & 63, wave = tid >> 6;
  const int wm = (wave >> 1) * 64, wn = (wave & 1) * 64;
  const int fr = lane & 15, q = lane >> 4;
  // fragment chunk positions for k-halves 0/32 (2-way bank aliasing = free)
  const int f0 = ((q)     ^ (fr & 7)) << 3;
  const int f1 = ((4 + q) ^ (fr & 7)) << 3;

  // per-thread staging: 4 A-chunks + 4 B-chunks per iter (1024 chunks/matrix)
  const unsigned short* aP[4];
  const unsigned short* bP[4];
  unsigned short* dA[4];
  unsigned short* dB[4];
#pragma unroll
  for (int p = 0; p < 4; ++p) {
    int l = p * 256 + tid;
    int r = l >> 3;
    int cg = (l & 7) ^ (r & 7);
    aP[p] = A  + (size_t)batch * sA + kOff + (size_t)(m0 + r) * LDA + cg * 8;
    bP[p] = Bm + (size_t)batch * sB + kOff + (size_t)(n0 + r) * LDB + cg * 8;
    dA[p] = &As[l * 8];
    dB[p] = &Bs[l * 8];
  }

  f32x4 acc[4][4] = {};
  for (int ko = 0; ko < K; ko += 64) {
    __syncthreads();
#pragma unroll
    for (int p = 0; p < 4; ++p) {
      gload16(aP[p], dA[p]); gload16(bP[p], dB[p]);
      aP[p] += 64; bP[p] += 64;
    }
    __syncthreads();
    {
      bf16x8 af[4], bfr[4];
#pragma unroll
      for (int i = 0; i < 4; ++i) af[i]  = *(const bf16x8*)&As[(wm + i * 16 + fr) * 64 + f0];
#pragma unroll
      for (int j = 0; j < 4; ++j) bfr[j] = *(const bf16x8*)&Bs[(wn + j * 16 + fr) * 64 + f0];
#pragma unroll
      for (int i = 0; i < 4; ++i)
#pragma unroll
        for (int j = 0; j < 4; ++j)
          acc[i][j] = __builtin_amdgcn_mfma_f32_16x16x32_bf16(af[i], bfr[j], acc[i][j], 0, 0, 0);
    }
    {
      bf16x8 af[4], bfr[4];
#pragma unroll
      for (int i = 0; i < 4; ++i) af[i]  = *(const bf16x8*)&As[(wm + i * 16 + fr) * 64 + f1];
#pragma unroll
      for (int j = 0; j < 4; ++j) bfr[j] = *(const bf16x8*)&Bs[(wn + j * 16 + fr) * 64 + f1];
#pragma unroll
      for (int i = 0; i < 4; ++i)
#pragma unroll
        for (int j = 0; j < 4; ++j)
          acc[i][j] = __builtin_amdgcn_mfma_f32_16x16x32_bf16(af[i], bfr[j], acc[i][j], 0, 0, 0);
    }
  }

  const int col = lane & 15, rbase = (lane >> 4) * 4;
#pragma unroll
  for (int i = 0; i < 4; ++i) {
#pragma unroll
    for (int j = 0; j < 4; ++j) {
      int gn = n0 + wn + j * 16 + col;
      int gmb = m0 + wm + i * 16 + rbase;
      float bv = (EPI == 2 || EPI == 8) ? bias[gn] : 0.0f;
#pragma unroll
      for (int r = 0; r < 4; ++r) {
        int gm = gmb + r;
        float v = acc[i][j][r] + bv;
        if (EPI == 2) {
          // gelu(v) ~= v * sigmoid(1.5957691*v + 0.0713548*v^3) (err < 3e-3)
          float u = v * (1.5957691216f + 0.0713548162f * v * v);
          float gl = v / (1.0f + exp2f(-L2E * u));
          ((unsigned short*)Cv)[(size_t)gm * LDC + gn] = f2bf(gl);
        } else if (EPI == 7) {
          ((float*)Cv)[(size_t)bz * sC + (size_t)gm * LDC + gn] = v;
        } else if (EPI == 8) {
          int sec = gn >> 10;          // 0=q 1=k 2=v
          int hh = (gn >> 6) & (H_ - 1);
          int dd = gn & 63;
          int t = gm & (T_ - 1);
          int b = gm >> 11;
          unsigned short bf = f2bf(v);
          if (sec == 0) {
            if (!(t & 7))
              aux1[(((size_t)(b * H_ + hh)) * QG + (t >> 3)) * 64 + dd] = bf;
          } else if (sec == 1) {
            aux2[(((size_t)(b * H_ + hh)) * T_ + t) * 64 + dd] = bf;
          } else {
            ((unsigned short*)Cv)[(size_t)gm * D_ + (gn - 2 * D_)] = bf;
          }
        }
      }
    }
  }
}

// ---------------- V transpose: v[tok, D] bf16 -> Vt[bh][d][t] bf16 -------
__global__ void vtrans_kernel(const unsigned short* __restrict__ vcomp,
                              unsigned short* __restrict__ Vt) {
  int blk = blockIdx.x;          // B*H*(T/64) = 1024
  int tchunk = blk & 31;
  int bh = blk >> 5;
  int h = bh & (H_ - 1), b = bh >> 4;
  int t0 = tchunk * 64;
  __shared__ unsigned short ls[64][66];
  int tid = threadIdx.x;
#pragma unroll
  for (int it = 0; it < 16; ++it) {
    int linear = it * 256 + tid;
    int d = linear & 63, tl = linear >> 6;
    ls[d][tl] = vcomp[((size_t)(b * T_ + t0 + tl)) * D_ + h * 64 + d];
  }
  __syncthreads();
#pragma unroll
  for (int it = 0; it < 16; ++it) {
    int linear = it * 256 + tid;
    int tl = linear & 63, d = linear >> 6;
    Vt[((size_t)(bh * 64 + d)) * T_ + t0 + tl] = ls[d][tl];
  }
}

// ---------------- Flash attention for global q-rows ----------------------
// grid (kchunk=4, qtile=4, bh=32), block 256 (4 waves; wave w owns q-rows
// qt*64 + w*16 .. +16). Each k-chunk covers 512 keys (4 tiles of 128).
__global__ __launch_bounds__(256)
void flash_kernel(const unsigned short* __restrict__ Qg,   // [bh][256][64]
                  const unsigned short* __restrict__ Kh,   // [bh][2048][64]
                  const unsigned short* __restrict__ Vt,   // [bh][64][2048]
                  float* __restrict__ Opart,               // [bh][4][256][64]
                  float* __restrict__ ml) {                // [bh][4][256][2]
  const int kc = blockIdx.x, qt = blockIdx.y, bh = blockIdx.z;
  const int tid = threadIdx.x;
  const int lane = tid & 63, w = tid >> 6;
  const int fr = lane & 15, quad = lane >> 4;

  __shared__ __align__(16) unsigned short Qs[64 * 64];     // 8 KB
  __shared__ __align__(16) unsigned short Ks[128 * 64];    // 16 KB
  __shared__ __align__(16) unsigned short Vs[64 * 128];    // 16 KB
  __shared__ __align__(16) unsigned short Ps[4 * 16 * 128];// 16 KB

  const unsigned short* Qbase = Qg + ((size_t)bh * 256 + qt * 64) * 64;
#pragma unroll
  for (int p = 0; p < 2; ++p) {
    int linear = p * 256 + tid;
    int r = linear >> 3, c = linear & 7;
    gload16(Qbase + r * 64 + (c ^ (r & 7)) * 8, &Qs[linear * 8]);
  }

  float m_run[4], l_run[4];
  f32x4 O[4] = {};
#pragma unroll
  for (int r = 0; r < 4; ++r) { m_run[r] = -3.0e38f; l_run[r] = 0.f; }

  const unsigned short* Kc = Kh + ((size_t)bh * T_ + kc * 512) * 64;
  const unsigned short* Vc = Vt + (size_t)bh * 64 * T_ + kc * 512;
  unsigned short* Pw = &Ps[w * 2048];
  const int arow = w * 16 + fr;

  for (int kt = 0; kt < 4; ++kt) {
    __syncthreads();
#pragma unroll
    for (int p = 0; p < 4; ++p) {
      int linear = p * 256 + tid;
      int r = linear >> 3, c = linear & 7;
      gload16(Kc + (size_t)(kt * 128 + r) * 64 + (c ^ (r & 7)) * 8, &Ks[linear * 8]);
    }
#pragma unroll
    for (int p = 0; p < 4; ++p) {
      int linear = p * 256 + tid;
      int r = linear >> 4, c = linear & 15;
      gload16(Vc + (size_t)r * T_ + kt * 128 + (c ^ (r & 7)) * 8, &Vs[linear * 8]);
    }
    __syncthreads();

    f32x4 s[8] = {};
    bf16x8 aq[2];
#pragma unroll
    for (int ks = 0; ks < 2; ++ks)
      aq[ks] = *(const bf16x8*)&Qs[arow * 64 + ((ks * 4 + quad) ^ (fr & 7)) * 8];
#pragma unroll
    for (int nf = 0; nf < 8; ++nf) {
      int krow = nf * 16 + fr;
#pragma unroll
      for (int ks = 0; ks < 2; ++ks) {
        bf16x8 bk = *(const bf16x8*)&Ks[krow * 64 + ((ks * 4 + quad) ^ (fr & 7)) * 8];
        s[nf] = __builtin_amdgcn_mfma_f32_16x16x32_bf16(aq[ks], bk, s[nf], 0, 0, 0);
      }
    }
    float alpha[4], rowsum[4];
#pragma unroll
    for (int r = 0; r < 4; ++r) {
      float mt = -3.0e38f;
#pragma unroll
      for (int nf = 0; nf < 8; ++nf) { s[nf][r] *= 0.125f; mt = fmaxf(mt, s[nf][r]); }
#pragma unroll
      for (int x = 1; x < 16; x <<= 1) mt = fmaxf(mt, __shfl_xor(mt, x, 64));
      float mn = fmaxf(m_run[r], mt);
      alpha[r] = exp2f((m_run[r] - mn) * L2E);
      m_run[r] = mn;
      rowsum[r] = 0.f;
    }
#pragma unroll
    for (int nf = 0; nf < 8; ++nf)
#pragma unroll
      for (int r = 0; r < 4; ++r) {
        float p = exp2f((s[nf][r] - m_run[r]) * L2E);
        s[nf][r] = p; rowsum[r] += p;
      }
#pragma unroll
    for (int r = 0; r < 4; ++r) {
#pragma unroll
      for (int x = 1; x < 16; x <<= 1) rowsum[r] += __shfl_xor(rowsum[r], x, 64);
      l_run[r] = l_run[r] * alpha[r] + rowsum[r];
    }
#pragma unroll
    for (int nf = 0; nf < 8; ++nf)
#pragma unroll
      for (int r = 0; r < 4; ++r) {
        int m = quad * 4 + r;
        int c = nf * 2 + (fr >> 3);
        Pw[m * 128 + ((c ^ (m & 7)) * 8) + (fr & 7)] = f2bf(s[nf][r]);
      }
#pragma unroll
    for (int nf2 = 0; nf2 < 4; ++nf2)
#pragma unroll
      for (int r = 0; r < 4; ++r) O[nf2][r] *= alpha[r];
#pragma unroll
    for (int ks2 = 0; ks2 < 4; ++ks2) {
      bf16x8 ap = *(const bf16x8*)&Pw[fr * 128 + (((ks2 * 4 + quad) ^ (fr & 7)) * 8)];
#pragma unroll
      for (int nf2 = 0; nf2 < 4; ++nf2) {
        int vrow = nf2 * 16 + fr;
        bf16x8 bv = *(const bf16x8*)&Vs[vrow * 128 + (((ks2 * 4 + quad) ^ (fr & 7)) * 8)];
        O[nf2] = __builtin_amdgcn_mfma_f32_16x16x32_bf16(ap, bv, O[nf2], 0, 0, 0);
      }
    }
  }

  int qbase = qt * 64 + w * 16;
  float* Ob = Opart + (((size_t)bh * 4 + kc) * 256 + qbase) * 64;
#pragma unroll
  for (int nf2 = 0; nf2 < 4; ++nf2)
#pragma unroll
    for (int r = 0; r < 4; ++r)
      Ob[(size_t)(quad * 4 + r) * 64 + nf2 * 16 + fr] = O[nf2][r];
  if (fr == 0) {
#pragma unroll
    for (int r = 0; r < 4; ++r) {
      size_t mi = ((((size_t)bh * 4 + kc) * 256) + qbase + quad * 4 + r) * 2;
      ml[mi] = m_run[r]; ml[mi + 1] = l_run[r];
    }
  }
}

// ---- combine 4 k-chunk flash partials, scatter into v buffer ------------
__global__ void combine_kernel(const float* __restrict__ Opart,
                               const float* __restrict__ ml,
                               unsigned short* __restrict__ vcomp) {
  int idx = blockIdx.x * 256 + threadIdx.x;  // B*QG*D = 2^19
  int c = idx & (D_ - 1);
  int qi = (idx >> 10) & (QG - 1);
  int b = idx >> 18;
  int h = c >> 6, d = c & 63;
  int bh = b * H_ + h;
  float m[4], l[4];
  float M = -3.0e38f;
#pragma unroll
  for (int ch = 0; ch < 4; ++ch) {
    size_t r = ((size_t)bh * 4 + ch) * 256 + qi;
    m[ch] = ml[r * 2]; l[ch] = ml[r * 2 + 1];
    M = fmaxf(M, m[ch]);
  }
  float osum = 0.f, lsum = 0.f;
#pragma unroll
  for (int ch = 0; ch < 4; ++ch) {
    size_t r = ((size_t)bh * 4 + ch) * 256 + qi;
    float wgt = exp2f((m[ch] - M) * L2E);
    osum += wgt * Opart[r * 64 + d];
    lsum += wgt * l[ch];
  }
  vcomp[((size_t)(b * T_ + qi * 8)) * D_ + c] = f2bf(osum / lsum);
}

extern "C" void kernel_launch(void* const* d_in, const int* in_sizes, int n_in,
                              void* d_out, int out_size, void* d_ws, size_t ws_size,
                              hipStream_t stream) {
  const float* x     = (const float*)d_in[0];
  const float* w_in  = (const float*)d_in[1];
  const float* b_in  = (const float*)d_in[2];
  const float* w_out = (const float*)d_in[3];
  const float* b_out = (const float*)d_in[4];
  const float* w1    = (const float*)d_in[5];
  const float* b1    = (const float*)d_in[6];
  const float* w2    = (const float*)d_in[7];
  const float* b2    = (const float*)d_in[8];
  const float* ln1_g = (const float*)d_in[9];
  const float* ln1_b = (const float*)d_in[10];
  const float* ln2_g = (const float*)d_in[11];
  const float* ln2_b = (const float*)d_in[12];
  float* out = (float*)d_out;

  char* ws = (char*)d_ws;
  size_t off = 0;
  auto alloc = [&](size_t bytes) -> void* {
    void* p = ws + off;
    off += (bytes + 255) & ~(size_t)255;
    return p;
  };
  unsigned short* xn    = (unsigned short*)alloc((size_t)NTOK * D_ * 2);
  unsigned short* vcomp = (unsigned short*)alloc((size_t)NTOK * D_ * 2);  // v, then o
  unsigned short* w_inb = (unsigned short*)alloc((size_t)3 * D_ * D_ * 2);
  unsigned short* w_outb= (unsigned short*)alloc((size_t)D_ * D_ * 2);
  unsigned short* w1b   = (unsigned short*)alloc((size_t)MLP_ * D_ * 2);
  unsigned short* w2b   = (unsigned short*)alloc((size_t)D_ * MLP_ * 2);
  unsigned short* Qg    = (unsigned short*)alloc((size_t)B_ * H_ * QG * 64 * 2);
  unsigned short* Kh    = (unsigned short*)alloc((size_t)B_ * H_ * T_ * 64 * 2);
  unsigned short* Vt    = (unsigned short*)alloc((size_t)B_ * H_ * 64 * T_ * 2);
  float*          Opart = (float*)         alloc((size_t)B_ * H_ * 4 * QG * 64 * 4);
  float*          mlbuf = (float*)         alloc((size_t)B_ * H_ * 4 * QG * 2 * 4);
  float*          x1    = (float*)         alloc((size_t)NTOK * D_ * 4);
  unsigned short* xn2   = (unsigned short*)alloc((size_t)NTOK * D_ * 2);
  unsigned short* h     = (unsigned short*)alloc((size_t)NTOK * MLP_ * 2);
  float*          P2    = (float*)         alloc((size_t)2 * NTOK * D_ * 4);

  // 1. weight casts (single launch)
  cast_all_kernel<<<(N4_WIN + N4_WOUT + N4_W1 + N4_W2) / 256, 256, 0, stream>>>(
      w_in, w_out, w1, w2, w_inb, w_outb, w1b, w2b);

  // 2. LN1
  ln_kernel<<<NTOK, 256, 0, stream>>>(x, ln1_g, ln1_b, xn);

  // 3. QKV = xn @ w_in^T + b_in; epilogue routes q->Qg, k->Kh, v->vcomp
  gemm_kernel<8, 2, D_, D_, 3 * D_><<<dim3(24 * 32, 1, 1), 256, 0, stream>>>(
      xn, 0, w_inb, 0, vcomp, 0, b_in, Qg, Kh, D_, 24, 32, 0);

  // 4. V transpose for PV B-operand
  vtrans_kernel<<<1024, 256, 0, stream>>>(vcomp, Vt);

  // 5. flash attention over global q-rows (k-split x4 -> 512 blocks)
  flash_kernel<<<dim3(4, 4, 32), 256, 0, stream>>>(Qg, Kh, Vt, Opart, mlbuf);

  // 6. combine k-chunks, scatter into v buffer (o = v elsewhere)
  combine_kernel<<<2048, 256, 0, stream>>>(Opart, mlbuf, vcomp);

  // 7. P2[c] = o @ w_out^T (k-chunk c)  (split-K x2, f32 partial slabs)
  gemm_kernel<7, 1, D_, D_, D_><<<dim3(8 * 32, 1, 2), 256, 0, stream>>>(
      vcomp, 0, w_outb, 0, P2, (size_t)NTOK * D_, nullptr, nullptr, nullptr,
      512, 8, 32, 1);

  // 8. x1 = x + b_out + sum(P2); xn2 = LN2(x1)   (fused reduce+LN)
  reduce_ln_kernel<<<NTOK, 256, 0, stream>>>(P2, x, b_out, ln2_g, ln2_b, x1, xn2);

  // 9. h = gelu(xn2 @ w1^T + b1) -> bf16 [4096, 4096]
  gemm_kernel<2, 2, D_, D_, MLP_><<<dim3(32 * 32, 1, 1), 256, 0, stream>>>(
      xn2, 0, w1b, 0, h, 0, b1, nullptr, nullptr, D_, 32, 32, 0);

  // 10. P2[c] = h @ w2^T (k-chunk c)  (split-K x2, f32 partial slabs)
  gemm_kernel<7, 1, MLP_, MLP_, D_><<<dim3(8 * 32, 1, 2), 256, 0, stream>>>(
      h, 0, w2b, 0, P2, (size_t)NTOK * D_, nullptr, nullptr, nullptr,
      2048, 8, 32, 1);

  // 11. out = x1 + b2 + sum(P2)
  reduce_out_kernel<<<4096, 256, 0, stream>>>(P2, x1, b2, out);
}